// Round 6
// baseline (455.182 us; speedup 1.0000x reference)
//
#include <hip/hip_runtime.h>

// ---- problem constants ----
#define HW     9216
#define NTOK   18432

typedef float  floatx4 __attribute__((ext_vector_type(4)));
typedef short  short8  __attribute__((ext_vector_type(8)));
typedef int    int4v   __attribute__((ext_vector_type(4)));

#if __has_builtin(__builtin_amdgcn_exp2f)
#define EXP2F(x) __builtin_amdgcn_exp2f(x)
#else
#define EXP2F(x) exp2f(x)
#endif

__device__ __forceinline__ unsigned short f2bf(float f) {   // RNE
  unsigned int u = __float_as_uint(f);
  u += 0x7fffu + ((u >> 16) & 1u);
  return (unsigned short)(u >> 16);
}
__device__ __forceinline__ float bf2f(unsigned short s) {
  return __uint_as_float(((unsigned int)s) << 16);
}
// pack two floats to bf16x2 (round-half-away)
__device__ __forceinline__ int pk2(float a, float b) {
  unsigned ua = __float_as_uint(a) + 0x8000u;
  unsigned ub = __float_as_uint(b) + 0x8000u;
  return (int)((ua >> 16) | (ub & 0xffff0000u));
}

// ======================================================================
// k_cnt: per-batch count of masked-out (0) pillars -> float. Needed for
// the mask-fold trick: masked keys have K=V=0 so p=exp2(0)=1 exactly;
// l_true = l_raw - nmask.
// ======================================================================
__global__ __launch_bounds__(256) void k_cnt(const int* __restrict__ mask,
                                             float* __restrict__ nmaskf)
{
  __shared__ int red[4];
  const int b = blockIdx.x, tid = threadIdx.x;
  int cnt = 0;
  for (int i = tid; i < HW; i += 256) cnt += (mask[b * HW + i] == 0);
  #pragma unroll
  for (int d = 1; d < 64; d <<= 1) cnt += __shfl_xor(cnt, d);
  if ((tid & 63) == 0) red[tid >> 6] = cnt;
  __syncthreads();
  if (tid == 0) nmaskf[b] = (float)(red[0] + red[1] + red[2] + red[3]);
}

// ======================================================================
// k_qkv: LN1 + Q/K/V projections (wave = 8 tokens). Q scaled by
// C^-0.5 * log2e (exp2 fold). K,V rows of MASKED tokens zeroed (mask
// fold). K/V written pre-swizzled in MFMA fragment-tile order. Also
// folds one-time prep (mask->float for k_post, wo/w1/w2 -> bf16).
// ======================================================================
__global__ __launch_bounds__(256) void k_qkv(
    const float* __restrict__ x,
    const float* __restrict__ wq, const float* __restrict__ bq,
    const float* __restrict__ wk, const float* __restrict__ bk,
    const float* __restrict__ wv, const float* __restrict__ bv,
    const float* __restrict__ g1, const float* __restrict__ b1,
    const int* __restrict__ mask,
    const float* __restrict__ wo, const float* __restrict__ w1,
    const float* __restrict__ w2,
    unsigned short* __restrict__ h_bf, unsigned short* __restrict__ qg,
    unsigned short* __restrict__ ksw, unsigned short* __restrict__ vsw,
    float* __restrict__ maskf, unsigned short* __restrict__ wobf,
    unsigned short* __restrict__ w1bf, unsigned short* __restrict__ w2bf)
{
  __shared__ float xt[64][33];
  __shared__ float hb[32][64];
  __shared__ unsigned short kt[32][72];
  __shared__ unsigned short vt[64][40];

  const int tid = threadIdx.x, wid = tid >> 6, c = tid & 63;
  const int bx = blockIdx.x;
  const int t0 = bx * 32;
  const int b  = t0 / HW, n0 = t0 % HW;

  if (tid < 32) maskf[t0 + tid] = mask[t0 + tid] ? 1.f : 0.f;
  if (bx < 16)       { const int i = bx * 256 + tid;        wobf[i] = f2bf(wo[i]); }
  else if (bx < 80)  { const int i = (bx - 16) * 256 + tid; w1bf[i] = f2bf(w1[i]); }
  else if (bx < 144) { const int i = (bx - 80) * 256 + tid; w2bf[i] = f2bf(w2[i]); }

  #pragma unroll
  for (int p = 0; p < 2; ++p) {
    const int idx = p * 256 + tid;
    const int cc = idx >> 3, t4 = (idx & 7) * 4;
    const floatx4 v = *(const floatx4*)(x + ((long)b * 64 + cc) * HW + n0 + t4);
    xt[cc][t4 + 0] = v[0]; xt[cc][t4 + 1] = v[1];
    xt[cc][t4 + 2] = v[2]; xt[cc][t4 + 3] = v[3];
  }
  __syncthreads();

  const float g1v = g1[c], b1v = b1[c];
  float aq[8], ak[8], av[8];
  const float bqv = bq[c], bkv = bk[c], bvv = bv[c];

  #pragma unroll
  for (int tt = 0; tt < 8; ++tt) {
    const int tok = wid * 8 + tt;
    const float val = xt[c][tok];
    float s = val, q = val * val;
    #pragma unroll
    for (int d = 1; d < 64; d <<= 1) { s += __shfl_xor(s, d); q += __shfl_xor(q, d); }
    const float mu  = s * (1.f / 64.f);
    const float var = q * (1.f / 64.f) - mu * mu;
    const float hv  = (val - mu) * rsqrtf(var + 1e-5f) * g1v + b1v;
    hb[tok][c] = hv;
    h_bf[(long)(t0 + tok) * 64 + c] = f2bf(hv);
    aq[tt] = bqv; ak[tt] = bkv; av[tt] = bvv;
  }

  const floatx4* wq4 = (const floatx4*)(wq + c * 64);
  const floatx4* wk4 = (const floatx4*)(wk + c * 64);
  const floatx4* wv4 = (const floatx4*)(wv + c * 64);
  #pragma unroll
  for (int i = 0; i < 16; ++i) {
    const floatx4 wqv = wq4[i], wkv = wk4[i], wvv = wv4[i];
    #pragma unroll
    for (int tt = 0; tt < 8; ++tt) {
      const floatx4 hh = *(const floatx4*)&hb[wid * 8 + tt][i * 4];
      aq[tt] = fmaf(wqv[0],hh[0], fmaf(wqv[1],hh[1], fmaf(wqv[2],hh[2], fmaf(wqv[3],hh[3], aq[tt]))));
      ak[tt] = fmaf(wkv[0],hh[0], fmaf(wkv[1],hh[1], fmaf(wkv[2],hh[2], fmaf(wkv[3],hh[3], ak[tt]))));
      av[tt] = fmaf(wvv[0],hh[0], fmaf(wvv[1],hh[1], fmaf(wvv[2],hh[2], fmaf(wvv[3],hh[3], av[tt]))));
    }
  }

  const float QSC = 0.125f * 1.44269504088896f;   // C^-0.5 * log2(e)
  #pragma unroll
  for (int tt = 0; tt < 8; ++tt) {
    const int tok = wid * 8 + tt;
    const float mk = mask[t0 + tok] ? 1.f : 0.f;   // mask fold: zero K,V rows
    qg[(long)(t0 + tok) * 64 + c] = f2bf(aq[tt] * QSC);
    kt[tok][c] = f2bf(ak[tt] * mk);
    vt[c][tok] = f2bf(av[tt] * mk);
  }
  __syncthreads();

  const long tile = (long)b * 288 + (n0 >> 5);
  {
    const int slot = tid >> 6, l = tid & 63;
    const int m = l & 15, qd = l >> 4, sub = slot >> 1, ss = slot & 1;
    const short8 v8 = *(const short8*)(&kt[sub * 16 + m][ss * 32 + qd * 8]);
    *(short8*)(ksw + tile * 2048 + tid * 8) = v8;
  }
  {
    const int f = tid >> 6, l = tid & 63;
    const int m = l & 15, qd = l >> 4;
    const short8 v8 = *(const short8*)(&vt[f * 16 + m][qd * 8]);
    *(short8*)(vsw + tile * 2048 + tid * 8) = v8;
  }
}

// ======================================================================
// k_attn (templated on SPLITS): flash attention, no online max, no mask
// in the hot loop (folded into K/V + l-correction). S^T = mfma(K,Q),
// exp2 directly on scores (log2e pre-folded into Q). P^T D->B via 8
// in-register shuffles. K/V double-buffered in LDS; waves own disjoint
// 48-query ranges. SPLITS=16: grid 1536 = 6 blocks/CU exact; split =
// bx&15 keeps each split's K/V slice XCD-L2-resident.
// ======================================================================
template<int SPLITS>
__global__ __launch_bounds__(256, 6) void k_attn(
    const unsigned short* __restrict__ qg, const unsigned short* __restrict__ ksw,
    const unsigned short* __restrict__ vsw,
    unsigned short* __restrict__ opart, float* __restrict__ lpart)
{
  constexpr int KIT = HW / SPLITS / 32;
  // [0,4096) K buf0 | [4096,8192) V buf0 | [8192,12288) K buf1 | [12288,16384) V buf1
  // epilogue overlays [0,17408) as per-wave fp32 transpose scratch
  __shared__ __align__(16) char smem[17408];

  const int tid = threadIdx.x, wid = tid >> 6, lane = tid & 63;
  const int mcol = lane & 15, quad = lane >> 4;
  const int bx = blockIdx.x;
  const int split = bx & (SPLITS - 1), qidx = bx / SPLITS;   // qidx 0..95
  const int b = qidx / 48, qt = qidx % 48;
  const long t0q = (long)b * HW + qt * 192 + wid * 48;

  const unsigned short* kswt = ksw + ((long)b * 288 + split * KIT) * 2048;
  const unsigned short* vswt = vsw + ((long)b * 288 + split * KIT) * 2048;

  short8 qf[3][2];
  #pragma unroll
  for (int g = 0; g < 3; ++g)
    #pragma unroll
    for (int s = 0; s < 2; ++s)
      qf[g][s] = *(const short8*)(qg + (t0q + g * 16 + mcol) * 64 + s * 32 + quad * 8);

  floatx4 oT[3][4];
  #pragma unroll
  for (int g = 0; g < 3; ++g)
    #pragma unroll
    for (int f = 0; f < 4; ++f) oT[g][f] = (floatx4){0.f,0.f,0.f,0.f};
  float lsum[3] = {0.f, 0.f, 0.f};

  const int slane = ((lane & 16) << 1) + mcol;
  const bool hi   = (lane & 32) != 0;

  short8 kr = *(const short8*)(kswt + tid * 8);
  short8 vr = *(const short8*)(vswt + tid * 8);
  *(short8*)((unsigned short*)smem + tid * 8) = kr;
  *(short8*)((unsigned short*)(smem + 4096) + tid * 8) = vr;
  __syncthreads();

  for (int it = 0; it < KIT; ++it) {
    const int off = (it & 1) * 8192;
    const unsigned short* kfc = (const unsigned short*)(smem + off);
    const unsigned short* vfc = (const unsigned short*)(smem + off + 4096);
    if (it + 1 < KIT) {
      kr = *(const short8*)(kswt + (it + 1) * 2048 + tid * 8);
      vr = *(const short8*)(vswt + (it + 1) * 2048 + tid * 8);
    }

    const short8 kA00 = *(const short8*)(kfc + (0 * 64 + lane) * 8);
    const short8 kA01 = *(const short8*)(kfc + (1 * 64 + lane) * 8);
    const short8 kA10 = *(const short8*)(kfc + (2 * 64 + lane) * 8);
    const short8 kA11 = *(const short8*)(kfc + (3 * 64 + lane) * 8);

    short8 pf[3];
    #pragma unroll
    for (int g = 0; g < 3; ++g) {
      floatx4 s0 = (floatx4){0.f,0.f,0.f,0.f}, s1 = (floatx4){0.f,0.f,0.f,0.f};
      s0 = __builtin_amdgcn_mfma_f32_16x16x32_bf16(kA00, qf[g][0], s0, 0, 0, 0);
      s0 = __builtin_amdgcn_mfma_f32_16x16x32_bf16(kA01, qf[g][1], s0, 0, 0, 0);
      s1 = __builtin_amdgcn_mfma_f32_16x16x32_bf16(kA10, qf[g][0], s1, 0, 0, 0);
      s1 = __builtin_amdgcn_mfma_f32_16x16x32_bf16(kA11, qf[g][1], s1, 0, 0, 0);

      float p0[4], p1[4];
      #pragma unroll
      for (int r = 0; r < 4; ++r) {
        p0[r] = EXP2F(s0[r]);     // masked keys: s=0 -> p=1 exactly (corrected via nmask)
        p1[r] = EXP2F(s1[r]);
      }
      lsum[g] += ((p0[0]+p0[1])+(p0[2]+p0[3])) + ((p1[0]+p1[1])+(p1[2]+p1[3]));

      const int u001 = pk2(p0[0], p0[1]), u023 = pk2(p0[2], p0[3]);
      const int u101 = pk2(p1[0], p1[1]), u123 = pk2(p1[2], p1[3]);
      const int a0 = __shfl(u001, slane),      b0 = __shfl(u101, slane);
      const int a1 = __shfl(u023, slane),      b1 = __shfl(u123, slane);
      const int a2 = __shfl(u001, slane + 16), b2 = __shfl(u101, slane + 16);
      const int a3 = __shfl(u023, slane + 16), b3 = __shfl(u123, slane + 16);
      int4v pv;
      pv[0] = hi ? b0 : a0; pv[1] = hi ? b1 : a1;
      pv[2] = hi ? b2 : a2; pv[3] = hi ? b3 : a3;
      pf[g] = __builtin_bit_cast(short8, pv);
    }

    #pragma unroll
    for (int f = 0; f < 4; ++f) {
      const short8 vA = *(const short8*)(vfc + (f * 64 + lane) * 8);
      #pragma unroll
      for (int g = 0; g < 3; ++g)
        oT[g][f] = __builtin_amdgcn_mfma_f32_16x16x32_bf16(vA, pf[g], oT[g][f], 0, 0, 0);
    }

    if (it + 1 < KIT) {
      unsigned short* kfn = (unsigned short*)(smem + (off ^ 8192));
      unsigned short* vfn = (unsigned short*)(smem + (off ^ 8192) + 4096);
      *(short8*)(kfn + tid * 8) = kr;
      *(short8*)(vfn + tid * 8) = vr;
    }
    __syncthreads();
  }

  // epilogue: per-wave fp32->bf16 transpose through (now free) LDS
  float* scr = (float*)smem + wid * 1088;    // 16 rows x 68
  #pragma unroll
  for (int g = 0; g < 3; ++g) {
    #pragma unroll
    for (int f = 0; f < 4; ++f)
      #pragma unroll
      for (int r = 0; r < 4; ++r)
        scr[(quad * 4 + r) * 68 + f * 16 + mcol] = oT[g][f][r];
    #pragma unroll
    for (int ps = 0; ps < 2; ++ps) {
      const int row = ps * 8 + (lane >> 3), cb = (lane & 7) * 8;
      const floatx4 a = *(const floatx4*)(scr + row * 68 + cb);
      const floatx4 c = *(const floatx4*)(scr + row * 68 + cb + 4);
      int4v pk;
      pk[0] = pk2(a[0], a[1]); pk[1] = pk2(a[2], a[3]);
      pk[2] = pk2(c[0], c[1]); pk[3] = pk2(c[2], c[3]);
      *(int4v*)(opart + ((long)split * NTOK + t0q + g * 16 + row) * 64 + cb) = pk;
    }
  }

  #pragma unroll
  for (int g = 0; g < 3; ++g) {
    float v = lsum[g];
    v += __shfl_xor(v, 16); v += __shfl_xor(v, 32);
    if (lane < 16) lpart[(long)split * NTOK + t0q + g * 16 + lane] = v;
  }
}

// ======================================================================
// k_post (templated on SPLITS): merge partials -> att (l corrected by
// nmask); wo-GEMM + residual; LN2; w1-GEMM + exact GELU; w2-GEMM +
// residual; mask; transposed coalesced store.
// ======================================================================
template<int SPLITS>
__global__ __launch_bounds__(256) void k_post(
    const unsigned short* __restrict__ opart, const float* __restrict__ lpart,
    const unsigned short* __restrict__ h_bf, const float* __restrict__ maskf,
    const float* __restrict__ nmaskf,
    const unsigned short* __restrict__ wobf, const float* __restrict__ bo,
    const float* __restrict__ g2, const float* __restrict__ b2,
    const unsigned short* __restrict__ w1bf, const float* __restrict__ bf1,
    const unsigned short* __restrict__ w2bf, const float* __restrict__ bf2,
    float* __restrict__ out)
{
  __shared__ float          h2_lds[32 * 68];
  __shared__ unsigned short att_lds[32 * 72];
  __shared__ unsigned short hn_lds[32 * 72];
  __shared__ unsigned short g_lds[32 * 264];
  __shared__ float          ot_lds[32 * 68];
  __shared__ float          linv[32];
  __shared__ float          st_mu[32], st_rs[32];

  const int tid = threadIdx.x, wid = tid >> 6, lane = tid & 63;
  const int mcol = lane & 15, quad = lane >> 4;
  const int t0 = blockIdx.x * 32;
  const int b = t0 / HW, n0 = t0 % HW;

  if (tid < 32) {
    float l = -nmaskf[b];           // mask-fold correction
    #pragma unroll
    for (int s = 0; s < SPLITS; ++s) l += lpart[(long)s * NTOK + t0 + tid];
    linv[tid] = 1.0f / l;
  }

  const int tok = tid >> 3, c8 = (tid & 7) * 8;
  float o[8];
  #pragma unroll
  for (int i = 0; i < 8; ++i) o[i] = 0.f;
  #pragma unroll
  for (int s = 0; s < SPLITS; ++s) {
    const short8 op = *(const short8*)(opart + ((long)s * NTOK + t0 + tok) * 64 + c8);
    #pragma unroll
    for (int i = 0; i < 8; ++i) o[i] += bf2f((unsigned short)op[i]);
  }
  const short8 hb8 = *(const short8*)(h_bf + (long)(t0 + tok) * 64 + c8);
  const floatx4 bo0 = *(const floatx4*)(bo + c8);
  const floatx4 bo1 = *(const floatx4*)(bo + c8 + 4);
  __syncthreads();
  {
    const float sc = linv[tok];
    int4v av;
    av[0] = pk2(o[0]*sc, o[1]*sc); av[1] = pk2(o[2]*sc, o[3]*sc);
    av[2] = pk2(o[4]*sc, o[5]*sc); av[3] = pk2(o[6]*sc, o[7]*sc);
    *(int4v*)(att_lds + tok * 72 + c8) = av;
    floatx4 h20, h21;
    #pragma unroll
    for (int i = 0; i < 4; ++i) {
      h20[i] = bf2f((unsigned short)hb8[i])     + bo0[i];
      h21[i] = bf2f((unsigned short)hb8[i + 4]) + bo1[i];
    }
    *(floatx4*)(h2_lds + tok * 68 + c8)     = h20;
    *(floatx4*)(h2_lds + tok * 68 + c8 + 4) = h21;
  }
  __syncthreads();

  const int Mt = wid & 1, nbase = (wid >> 1) * 2;
  {
    const short8 aA0 = *(const short8*)(att_lds + (Mt * 16 + mcol) * 72 + quad * 8);
    const short8 aA1 = *(const short8*)(att_lds + (Mt * 16 + mcol) * 72 + 32 + quad * 8);
    #pragma unroll
    for (int nt = 0; nt < 2; ++nt) {
      const int nc = (nbase + nt) * 16;
      const short8 b0 = *(const short8*)(wobf + (nc + mcol) * 64 + quad * 8);
      const short8 b1 = *(const short8*)(wobf + (nc + mcol) * 64 + 32 + quad * 8);
      floatx4 d = (floatx4){0.f,0.f,0.f,0.f};
      d = __builtin_amdgcn_mfma_f32_16x16x32_bf16(aA0, b0, d, 0, 0, 0);
      d = __builtin_amdgcn_mfma_f32_16x16x32_bf16(aA1, b1, d, 0, 0, 0);
      #pragma unroll
      for (int r = 0; r < 4; ++r)
        h2_lds[(Mt * 16 + quad * 4 + r) * 68 + nc + mcol] += d[r];
    }
  }
  __syncthreads();

  {
    floatx4 v0 = *(const floatx4*)(h2_lds + tok * 68 + c8);
    floatx4 v1 = *(const floatx4*)(h2_lds + tok * 68 + c8 + 4);
    float s1 = (v0[0]+v0[1])+(v0[2]+v0[3]) + (v1[0]+v1[1])+(v1[2]+v1[3]);
    float s2 = (v0[0]*v0[0]+v0[1]*v0[1])+(v0[2]*v0[2]+v0[3]*v0[3])
             + (v1[0]*v1[0]+v1[1]*v1[1])+(v1[2]*v1[2]+v1[3]*v1[3]);
    #pragma unroll
    for (int d = 1; d < 8; d <<= 1) { s1 += __shfl_xor(s1, d); s2 += __shfl_xor(s2, d); }
    if ((tid & 7) == 0) {
      const float mu = s1 * (1.f / 64.f);
      const float var = s2 * (1.f / 64.f) - mu * mu;
      st_mu[tok] = mu; st_rs[tok] = rsqrtf(var + 1e-5f);
    }
  }
  __syncthreads();

  {
    const float mu = st_mu[tok], rs = st_rs[tok];
    const floatx4 v0 = *(const floatx4*)(h2_lds + tok * 68 + c8);
    const floatx4 v1 = *(const floatx4*)(h2_lds + tok * 68 + c8 + 4);
    const floatx4 ga = *(const floatx4*)(g2 + c8), gb = *(const floatx4*)(g2 + c8 + 4);
    const floatx4 ba = *(const floatx4*)(b2 + c8), bb = *(const floatx4*)(b2 + c8 + 4);
    float hn[8];
    #pragma unroll
    for (int i = 0; i < 4; ++i) {
      hn[i]     = (v0[i] - mu) * rs * ga[i] + ba[i];
      hn[i + 4] = (v1[i] - mu) * rs * gb[i] + bb[i];
    }
    int4v hv;
    hv[0] = pk2(hn[0], hn[1]); hv[1] = pk2(hn[2], hn[3]);
    hv[2] = pk2(hn[4], hn[5]); hv[3] = pk2(hn[6], hn[7]);
    *(int4v*)(hn_lds + tok * 72 + c8) = hv;
  }
  __syncthreads();

  {
    const short8 aA0 = *(const short8*)(hn_lds + (Mt * 16 + mcol) * 72 + quad * 8);
    const short8 aA1 = *(const short8*)(hn_lds + (Mt * 16 + mcol) * 72 + 32 + quad * 8);
    #pragma unroll
    for (int nt = 0; nt < 8; ++nt) {
      const int u0 = ((wid >> 1) * 8 + nt) * 16;
      const short8 b0 = *(const short8*)(w1bf + (u0 + mcol) * 64 + quad * 8);
      const short8 b1 = *(const short8*)(w1bf + (u0 + mcol) * 64 + 32 + quad * 8);
      floatx4 d = (floatx4){0.f,0.f,0.f,0.f};
      d = __builtin_amdgcn_mfma_f32_16x16x32_bf16(aA0, b0, d, 0, 0, 0);
      d = __builtin_amdgcn_mfma_f32_16x16x32_bf16(aA1, b1, d, 0, 0, 0);
      const float bf1v = bf1[u0 + mcol];
      #pragma unroll
      for (int r = 0; r < 4; ++r) {
        const float a = d[r] + bf1v;
        const float gl = 0.5f * a * (1.0f + erff(a * 0.70710678118654752f));
        g_lds[(Mt * 16 + quad * 4 + r) * 264 + u0 + mcol] = f2bf(gl);
      }
    }
  }
  __syncthreads();

  {
    floatx4 acc[2];
    acc[0] = (floatx4){0.f,0.f,0.f,0.f}; acc[1] = (floatx4){0.f,0.f,0.f,0.f};
    #pragma unroll
    for (int ks = 0; ks < 8; ++ks) {
      const short8 aA = *(const short8*)(g_lds + (Mt * 16 + mcol) * 264 + ks * 32 + quad * 8);
      #pragma unroll
      for (int nt = 0; nt < 2; ++nt) {
        const int nc = (nbase + nt) * 16;
        const short8 bB = *(const short8*)(w2bf + (nc + mcol) * 256 + ks * 32 + quad * 8);
        acc[nt] = __builtin_amdgcn_mfma_f32_16x16x32_bf16(aA, bB, acc[nt], 0, 0, 0);
      }
    }
    #pragma unroll
    for (int nt = 0; nt < 2; ++nt) {
      const int cc = (nbase + nt) * 16 + mcol;
      const float g2v = g2[cc], b2v = b2[cc], bf2v = bf2[cc];
      #pragma unroll
      for (int r = 0; r < 4; ++r) {
        const int tokr = Mt * 16 + quad * 4 + r;
        const float hn = (h2_lds[tokr * 68 + cc] - st_mu[tokr]) * st_rs[tokr] * g2v + b2v;
        const float o2 = (hn + acc[nt][r] + bf2v) * maskf[t0 + tokr];
        ot_lds[tokr * 68 + cc] = o2;
      }
    }
  }
  __syncthreads();

  {
    const int c = tid >> 2, tg = (tid & 3) * 8;
    floatx4 v0, v1;
    #pragma unroll
    for (int i = 0; i < 4; ++i) {
      v0[i] = ot_lds[(tg + i) * 68 + c];
      v1[i] = ot_lds[(tg + 4 + i) * 68 + c];
    }
    float* dst = out + ((long)b * 64 + c) * HW + n0 + tg;
    *(floatx4*)dst = v0;
    *(floatx4*)(dst + 4) = v1;
  }
}

// ======================================================================
extern "C" void kernel_launch(void* const* d_in, const int* in_sizes, int n_in,
                              void* d_out, int out_size, void* d_ws, size_t ws_size,
                              hipStream_t stream) {
  (void)in_sizes; (void)n_in; (void)out_size;
  const float* x   = (const float*)d_in[0];
  const int*   msk = (const int*)  d_in[1];
  const float* wq  = (const float*)d_in[2];
  const float* bq  = (const float*)d_in[3];
  const float* wk  = (const float*)d_in[4];
  const float* bk  = (const float*)d_in[5];
  const float* wv  = (const float*)d_in[6];
  const float* bv  = (const float*)d_in[7];
  const float* wo  = (const float*)d_in[8];
  const float* bo  = (const float*)d_in[9];
  const float* g1  = (const float*)d_in[10];
  const float* b1  = (const float*)d_in[11];
  const float* g2  = (const float*)d_in[12];
  const float* b2  = (const float*)d_in[13];
  const float* w1  = (const float*)d_in[14];
  const float* bf1 = (const float*)d_in[15];
  const float* w2  = (const float*)d_in[16];
  const float* bf2 = (const float*)d_in[17];
  float* out = (float*)d_out;

  // SPLITS=16 needs ~48.5 MB of workspace; fall back to 8 if unavailable.
  const size_t NEED16 = 48513056ull;
  const int splits = (ws_size >= NEED16) ? 16 : 8;

  char* ws = (char*)d_ws;
  size_t off = 0;
  unsigned short* h_bf  = (unsigned short*)(ws + off); off += 2359296;
  unsigned short* qg    = (unsigned short*)(ws + off); off += 2359296;
  unsigned short* ksw   = (unsigned short*)(ws + off); off += 2359296;
  unsigned short* vsw   = (unsigned short*)(ws + off); off += 2359296;
  unsigned short* opart = (unsigned short*)(ws + off); off += (size_t)splits * NTOK * 64 * 2;
  float*          lpart = (float*)(ws + off);          off += (size_t)splits * NTOK * 4;
  float*          maskf = (float*)(ws + off);          off += 73728;
  unsigned short* wobf  = (unsigned short*)(ws + off); off += 8192;
  unsigned short* w1bf  = (unsigned short*)(ws + off); off += 32768;
  unsigned short* w2bf  = (unsigned short*)(ws + off); off += 32768;
  float*          nmaskf= (float*)(ws + off);          off += 16;

  k_cnt<<<dim3(2),   dim3(256), 0, stream>>>(msk, nmaskf);
  k_qkv<<<dim3(576), dim3(256), 0, stream>>>(
      x, wq, bq, wk, bk, wv, bv, g1, b1, msk, wo, w1, w2,
      h_bf, qg, ksw, vsw, maskf, wobf, w1bf, w2bf);
  if (splits == 16) {
    k_attn<16><<<dim3(96 * 16), dim3(256), 0, stream>>>(qg, ksw, vsw, opart, lpart);
    k_post<16><<<dim3(576),     dim3(256), 0, stream>>>(
        opart, lpart, h_bf, maskf, nmaskf, wobf, bo, g2, b2, w1bf, bf1, w2bf, bf2, out);
  } else {
    k_attn<8><<<dim3(96 * 8), dim3(256), 0, stream>>>(qg, ksw, vsw, opart, lpart);
    k_post<8><<<dim3(576),    dim3(256), 0, stream>>>(
        opart, lpart, h_bf, maskf, nmaskf, wobf, bo, g2, b2, w1bf, bf1, w2bf, bf2, out);
  }
}

// Round 7
// 203.553 us; speedup vs baseline: 2.2362x; 2.2362x over previous
//
#include <hip/hip_runtime.h>

// ---- problem constants ----
#define HW     9216
#define NTOK   18432

typedef float  floatx4 __attribute__((ext_vector_type(4)));
typedef short  short8  __attribute__((ext_vector_type(8)));
typedef int    int4v   __attribute__((ext_vector_type(4)));

#if __has_builtin(__builtin_amdgcn_exp2f)
#define EXP2F(x) __builtin_amdgcn_exp2f(x)
#else
#define EXP2F(x) exp2f(x)
#endif

__device__ __forceinline__ unsigned short f2bf(float f) {   // RNE
  unsigned int u = __float_as_uint(f);
  u += 0x7fffu + ((u >> 16) & 1u);
  return (unsigned short)(u >> 16);
}
__device__ __forceinline__ float bf2f(unsigned short s) {
  return __uint_as_float(((unsigned int)s) << 16);
}
// pack two floats to bf16x2 (round-half-away)
__device__ __forceinline__ int pk2(float a, float b) {
  unsigned ua = __float_as_uint(a) + 0x8000u;
  unsigned ub = __float_as_uint(b) + 0x8000u;
  return (int)((ua >> 16) | (ub & 0xffff0000u));
}

// ======================================================================
// k_qkv: LN1 + Q/K/V projections (wave = 8 tokens). Q scaled by
// C^-0.5 * log2e (exp2 fold). K,V rows of MASKED tokens zeroed (mask
// fold; masked keys contribute p=exp2(0)=1 -> corrected via nmaskf,
// accumulated here by per-block ballot + atomicAdd). K/V written
// pre-swizzled in MFMA fragment-tile order. Also folds one-time prep
// (mask->float for k_post, wo/w1/w2 -> bf16).
// ======================================================================
__global__ __launch_bounds__(256) void k_qkv(
    const float* __restrict__ x,
    const float* __restrict__ wq, const float* __restrict__ bq,
    const float* __restrict__ wk, const float* __restrict__ bk,
    const float* __restrict__ wv, const float* __restrict__ bv,
    const float* __restrict__ g1, const float* __restrict__ b1,
    const int* __restrict__ mask,
    const float* __restrict__ wo, const float* __restrict__ w1,
    const float* __restrict__ w2,
    unsigned short* __restrict__ h_bf, unsigned short* __restrict__ qg,
    unsigned short* __restrict__ ksw, unsigned short* __restrict__ vsw,
    float* __restrict__ maskf, unsigned short* __restrict__ wobf,
    unsigned short* __restrict__ w1bf, unsigned short* __restrict__ w2bf,
    float* __restrict__ nmaskf)
{
  __shared__ float xt[64][33];
  __shared__ float hb[32][64];
  __shared__ unsigned short kt[32][72];
  __shared__ unsigned short vt[64][40];

  const int tid = threadIdx.x, wid = tid >> 6, c = tid & 63;
  const int bx = blockIdx.x;
  const int t0 = bx * 32;
  const int b  = t0 / HW, n0 = t0 % HW;

  if (tid < 32) maskf[t0 + tid] = mask[t0 + tid] ? 1.f : 0.f;
  // nmask count for this block's 32 tokens (wave 0 ballot; nmaskf pre-zeroed)
  if (wid == 0) {
    const bool mm = (c < 32) ? (mask[t0 + c] == 0) : false;
    const unsigned long long bal = __ballot(mm);
    if (c == 0 && bal) atomicAdd(&nmaskf[b], (float)__popcll(bal));
  }
  if (bx < 16)       { const int i = bx * 256 + tid;        wobf[i] = f2bf(wo[i]); }
  else if (bx < 80)  { const int i = (bx - 16) * 256 + tid; w1bf[i] = f2bf(w1[i]); }
  else if (bx < 144) { const int i = (bx - 80) * 256 + tid; w2bf[i] = f2bf(w2[i]); }

  #pragma unroll
  for (int p = 0; p < 2; ++p) {
    const int idx = p * 256 + tid;
    const int cc = idx >> 3, t4 = (idx & 7) * 4;
    const floatx4 v = *(const floatx4*)(x + ((long)b * 64 + cc) * HW + n0 + t4);
    xt[cc][t4 + 0] = v[0]; xt[cc][t4 + 1] = v[1];
    xt[cc][t4 + 2] = v[2]; xt[cc][t4 + 3] = v[3];
  }
  __syncthreads();

  const float g1v = g1[c], b1v = b1[c];
  float aq[8], ak[8], av[8];
  const float bqv = bq[c], bkv = bk[c], bvv = bv[c];

  #pragma unroll
  for (int tt = 0; tt < 8; ++tt) {
    const int tok = wid * 8 + tt;
    const float val = xt[c][tok];
    float s = val, q = val * val;
    #pragma unroll
    for (int d = 1; d < 64; d <<= 1) { s += __shfl_xor(s, d); q += __shfl_xor(q, d); }
    const float mu  = s * (1.f / 64.f);
    const float var = q * (1.f / 64.f) - mu * mu;
    const float hv  = (val - mu) * rsqrtf(var + 1e-5f) * g1v + b1v;
    hb[tok][c] = hv;
    h_bf[(long)(t0 + tok) * 64 + c] = f2bf(hv);
    aq[tt] = bqv; ak[tt] = bkv; av[tt] = bvv;
  }

  const floatx4* wq4 = (const floatx4*)(wq + c * 64);
  const floatx4* wk4 = (const floatx4*)(wk + c * 64);
  const floatx4* wv4 = (const floatx4*)(wv + c * 64);
  #pragma unroll
  for (int i = 0; i < 16; ++i) {
    const floatx4 wqv = wq4[i], wkv = wk4[i], wvv = wv4[i];
    #pragma unroll
    for (int tt = 0; tt < 8; ++tt) {
      const floatx4 hh = *(const floatx4*)&hb[wid * 8 + tt][i * 4];
      aq[tt] = fmaf(wqv[0],hh[0], fmaf(wqv[1],hh[1], fmaf(wqv[2],hh[2], fmaf(wqv[3],hh[3], aq[tt]))));
      ak[tt] = fmaf(wkv[0],hh[0], fmaf(wkv[1],hh[1], fmaf(wkv[2],hh[2], fmaf(wkv[3],hh[3], ak[tt]))));
      av[tt] = fmaf(wvv[0],hh[0], fmaf(wvv[1],hh[1], fmaf(wvv[2],hh[2], fmaf(wvv[3],hh[3], av[tt]))));
    }
  }

  const float QSC = 0.125f * 1.44269504088896f;   // C^-0.5 * log2(e)
  #pragma unroll
  for (int tt = 0; tt < 8; ++tt) {
    const int tok = wid * 8 + tt;
    const float mk = mask[t0 + tok] ? 1.f : 0.f;   // mask fold: zero K,V rows
    qg[(long)(t0 + tok) * 64 + c] = f2bf(aq[tt] * QSC);
    kt[tok][c] = f2bf(ak[tt] * mk);
    vt[c][tok] = f2bf(av[tt] * mk);
  }
  __syncthreads();

  const long tile = (long)b * 288 + (n0 >> 5);
  {
    const int slot = tid >> 6, l = tid & 63;
    const int m = l & 15, qd = l >> 4, sub = slot >> 1, ss = slot & 1;
    const short8 v8 = *(const short8*)(&kt[sub * 16 + m][ss * 32 + qd * 8]);
    *(short8*)(ksw + tile * 2048 + tid * 8) = v8;
  }
  {
    const int f = tid >> 6, l = tid & 63;
    const int m = l & 15, qd = l >> 4;
    const short8 v8 = *(const short8*)(&vt[f * 16 + m][qd * 8]);
    *(short8*)(vsw + tile * 2048 + tid * 8) = v8;
  }
}

// ======================================================================
// k_attn (templated on SPLITS): flash attention, no online max, no mask
// in the hot loop. S^T = mfma(K,Q), exp2 directly on scores. P^T D->B
// via 8 in-register shuffles. K/V double-buffered in LDS; waves own
// disjoint 48-query ranges. Grid 96*SPLITS.
// launch_bounds(256,4): cap 128 VGPRs -- compiler settles ~80, NO SPILLS
// (round 6's (256,6) cap forced VGPR=40 -> 1.47 GB scratch spill traffic,
// 4x regression). At 80 VGPRs HW allows 6 waves/SIMD -> up to 6 blocks/CU.
// ======================================================================
template<int SPLITS>
__global__ __launch_bounds__(256, 4) void k_attn(
    const unsigned short* __restrict__ qg, const unsigned short* __restrict__ ksw,
    const unsigned short* __restrict__ vsw,
    unsigned short* __restrict__ opart, float* __restrict__ lpart)
{
  constexpr int KIT = HW / SPLITS / 32;
  // [0,4096) K buf0 | [4096,8192) V buf0 | [8192,12288) K buf1 | [12288,16384) V buf1
  // epilogue overlays [0,17408) as per-wave fp32 transpose scratch
  __shared__ __align__(16) char smem[17408];

  const int tid = threadIdx.x, wid = tid >> 6, lane = tid & 63;
  const int mcol = lane & 15, quad = lane >> 4;
  const int bx = blockIdx.x;
  const int split = bx & (SPLITS - 1), qidx = bx / SPLITS;   // qidx 0..95
  const int b = qidx / 48, qt = qidx % 48;
  const long t0q = (long)b * HW + qt * 192 + wid * 48;

  const unsigned short* kswt = ksw + ((long)b * 288 + split * KIT) * 2048;
  const unsigned short* vswt = vsw + ((long)b * 288 + split * KIT) * 2048;

  short8 qf[3][2];
  #pragma unroll
  for (int g = 0; g < 3; ++g)
    #pragma unroll
    for (int s = 0; s < 2; ++s)
      qf[g][s] = *(const short8*)(qg + (t0q + g * 16 + mcol) * 64 + s * 32 + quad * 8);

  floatx4 oT[3][4];
  #pragma unroll
  for (int g = 0; g < 3; ++g)
    #pragma unroll
    for (int f = 0; f < 4; ++f) oT[g][f] = (floatx4){0.f,0.f,0.f,0.f};
  float lsum[3] = {0.f, 0.f, 0.f};

  const int slane = ((lane & 16) << 1) + mcol;
  const bool hi   = (lane & 32) != 0;

  short8 kr = *(const short8*)(kswt + tid * 8);
  short8 vr = *(const short8*)(vswt + tid * 8);
  *(short8*)((unsigned short*)smem + tid * 8) = kr;
  *(short8*)((unsigned short*)(smem + 4096) + tid * 8) = vr;
  __syncthreads();

  for (int it = 0; it < KIT; ++it) {
    const int off = (it & 1) * 8192;
    const unsigned short* kfc = (const unsigned short*)(smem + off);
    const unsigned short* vfc = (const unsigned short*)(smem + off + 4096);
    if (it + 1 < KIT) {
      kr = *(const short8*)(kswt + (it + 1) * 2048 + tid * 8);
      vr = *(const short8*)(vswt + (it + 1) * 2048 + tid * 8);
    }

    const short8 kA00 = *(const short8*)(kfc + (0 * 64 + lane) * 8);
    const short8 kA01 = *(const short8*)(kfc + (1 * 64 + lane) * 8);
    const short8 kA10 = *(const short8*)(kfc + (2 * 64 + lane) * 8);
    const short8 kA11 = *(const short8*)(kfc + (3 * 64 + lane) * 8);

    short8 pf[3];
    #pragma unroll
    for (int g = 0; g < 3; ++g) {
      floatx4 s0 = (floatx4){0.f,0.f,0.f,0.f}, s1 = (floatx4){0.f,0.f,0.f,0.f};
      s0 = __builtin_amdgcn_mfma_f32_16x16x32_bf16(kA00, qf[g][0], s0, 0, 0, 0);
      s0 = __builtin_amdgcn_mfma_f32_16x16x32_bf16(kA01, qf[g][1], s0, 0, 0, 0);
      s1 = __builtin_amdgcn_mfma_f32_16x16x32_bf16(kA10, qf[g][0], s1, 0, 0, 0);
      s1 = __builtin_amdgcn_mfma_f32_16x16x32_bf16(kA11, qf[g][1], s1, 0, 0, 0);

      float p0[4], p1[4];
      #pragma unroll
      for (int r = 0; r < 4; ++r) {
        p0[r] = EXP2F(s0[r]);     // masked keys: s=0 -> p=1 exactly (corrected via nmask)
        p1[r] = EXP2F(s1[r]);
      }
      lsum[g] += ((p0[0]+p0[1])+(p0[2]+p0[3])) + ((p1[0]+p1[1])+(p1[2]+p1[3]));

      const int u001 = pk2(p0[0], p0[1]), u023 = pk2(p0[2], p0[3]);
      const int u101 = pk2(p1[0], p1[1]), u123 = pk2(p1[2], p1[3]);
      const int a0 = __shfl(u001, slane),      b0 = __shfl(u101, slane);
      const int a1 = __shfl(u023, slane),      b1 = __shfl(u123, slane);
      const int a2 = __shfl(u001, slane + 16), b2 = __shfl(u101, slane + 16);
      const int a3 = __shfl(u023, slane + 16), b3 = __shfl(u123, slane + 16);
      int4v pv;
      pv[0] = hi ? b0 : a0; pv[1] = hi ? b1 : a1;
      pv[2] = hi ? b2 : a2; pv[3] = hi ? b3 : a3;
      pf[g] = __builtin_bit_cast(short8, pv);
    }

    #pragma unroll
    for (int f = 0; f < 4; ++f) {
      const short8 vA = *(const short8*)(vfc + (f * 64 + lane) * 8);
      #pragma unroll
      for (int g = 0; g < 3; ++g)
        oT[g][f] = __builtin_amdgcn_mfma_f32_16x16x32_bf16(vA, pf[g], oT[g][f], 0, 0, 0);
    }

    if (it + 1 < KIT) {
      unsigned short* kfn = (unsigned short*)(smem + (off ^ 8192));
      unsigned short* vfn = (unsigned short*)(smem + (off ^ 8192) + 4096);
      *(short8*)(kfn + tid * 8) = kr;
      *(short8*)(vfn + tid * 8) = vr;
    }
    __syncthreads();
  }

  // epilogue: per-wave fp32->bf16 transpose through (now free) LDS
  float* scr = (float*)smem + wid * 1088;    // 16 rows x 68
  #pragma unroll
  for (int g = 0; g < 3; ++g) {
    #pragma unroll
    for (int f = 0; f < 4; ++f)
      #pragma unroll
      for (int r = 0; r < 4; ++r)
        scr[(quad * 4 + r) * 68 + f * 16 + mcol] = oT[g][f][r];
    #pragma unroll
    for (int ps = 0; ps < 2; ++ps) {
      const int row = ps * 8 + (lane >> 3), cb = (lane & 7) * 8;
      const floatx4 a = *(const floatx4*)(scr + row * 68 + cb);
      const floatx4 c = *(const floatx4*)(scr + row * 68 + cb + 4);
      int4v pk;
      pk[0] = pk2(a[0], a[1]); pk[1] = pk2(a[2], a[3]);
      pk[2] = pk2(c[0], c[1]); pk[3] = pk2(c[2], c[3]);
      *(int4v*)(opart + ((long)split * NTOK + t0q + g * 16 + row) * 64 + cb) = pk;
    }
  }

  #pragma unroll
  for (int g = 0; g < 3; ++g) {
    float v = lsum[g];
    v += __shfl_xor(v, 16); v += __shfl_xor(v, 32);
    if (lane < 16) lpart[(long)split * NTOK + t0q + g * 16 + lane] = v;
  }
}

// ======================================================================
// k_post (templated on SPLITS): merge partials -> att (l corrected by
// nmask); wo-GEMM + residual; LN2; w1-GEMM + exact GELU; w2-GEMM +
// residual; mask; transposed coalesced store.
// ======================================================================
template<int SPLITS>
__global__ __launch_bounds__(256) void k_post(
    const unsigned short* __restrict__ opart, const float* __restrict__ lpart,
    const unsigned short* __restrict__ h_bf, const float* __restrict__ maskf,
    const float* __restrict__ nmaskf,
    const unsigned short* __restrict__ wobf, const float* __restrict__ bo,
    const float* __restrict__ g2, const float* __restrict__ b2,
    const unsigned short* __restrict__ w1bf, const float* __restrict__ bf1,
    const unsigned short* __restrict__ w2bf, const float* __restrict__ bf2,
    float* __restrict__ out)
{
  __shared__ float          h2_lds[32 * 68];
  __shared__ unsigned short att_lds[32 * 72];
  __shared__ unsigned short hn_lds[32 * 72];
  __shared__ unsigned short g_lds[32 * 264];
  __shared__ float          ot_lds[32 * 68];
  __shared__ float          linv[32];
  __shared__ float          st_mu[32], st_rs[32];

  const int tid = threadIdx.x, wid = tid >> 6, lane = tid & 63;
  const int mcol = lane & 15, quad = lane >> 4;
  const int t0 = blockIdx.x * 32;
  const int b = t0 / HW, n0 = t0 % HW;

  if (tid < 32) {
    float l = -nmaskf[b];           // mask-fold correction
    #pragma unroll
    for (int s = 0; s < SPLITS; ++s) l += lpart[(long)s * NTOK + t0 + tid];
    linv[tid] = 1.0f / l;
  }

  const int tok = tid >> 3, c8 = (tid & 7) * 8;
  float o[8];
  #pragma unroll
  for (int i = 0; i < 8; ++i) o[i] = 0.f;
  #pragma unroll
  for (int s = 0; s < SPLITS; ++s) {
    const short8 op = *(const short8*)(opart + ((long)s * NTOK + t0 + tok) * 64 + c8);
    #pragma unroll
    for (int i = 0; i < 8; ++i) o[i] += bf2f((unsigned short)op[i]);
  }
  const short8 hb8 = *(const short8*)(h_bf + (long)(t0 + tok) * 64 + c8);
  const floatx4 bo0 = *(const floatx4*)(bo + c8);
  const floatx4 bo1 = *(const floatx4*)(bo + c8 + 4);
  __syncthreads();
  {
    const float sc = linv[tok];
    int4v av;
    av[0] = pk2(o[0]*sc, o[1]*sc); av[1] = pk2(o[2]*sc, o[3]*sc);
    av[2] = pk2(o[4]*sc, o[5]*sc); av[3] = pk2(o[6]*sc, o[7]*sc);
    *(int4v*)(att_lds + tok * 72 + c8) = av;
    floatx4 h20, h21;
    #pragma unroll
    for (int i = 0; i < 4; ++i) {
      h20[i] = bf2f((unsigned short)hb8[i])     + bo0[i];
      h21[i] = bf2f((unsigned short)hb8[i + 4]) + bo1[i];
    }
    *(floatx4*)(h2_lds + tok * 68 + c8)     = h20;
    *(floatx4*)(h2_lds + tok * 68 + c8 + 4) = h21;
  }
  __syncthreads();

  const int Mt = wid & 1, nbase = (wid >> 1) * 2;
  {
    const short8 aA0 = *(const short8*)(att_lds + (Mt * 16 + mcol) * 72 + quad * 8);
    const short8 aA1 = *(const short8*)(att_lds + (Mt * 16 + mcol) * 72 + 32 + quad * 8);
    #pragma unroll
    for (int nt = 0; nt < 2; ++nt) {
      const int nc = (nbase + nt) * 16;
      const short8 b0 = *(const short8*)(wobf + (nc + mcol) * 64 + quad * 8);
      const short8 b1 = *(const short8*)(wobf + (nc + mcol) * 64 + 32 + quad * 8);
      floatx4 d = (floatx4){0.f,0.f,0.f,0.f};
      d = __builtin_amdgcn_mfma_f32_16x16x32_bf16(aA0, b0, d, 0, 0, 0);
      d = __builtin_amdgcn_mfma_f32_16x16x32_bf16(aA1, b1, d, 0, 0, 0);
      #pragma unroll
      for (int r = 0; r < 4; ++r)
        h2_lds[(Mt * 16 + quad * 4 + r) * 68 + nc + mcol] += d[r];
    }
  }
  __syncthreads();

  {
    floatx4 v0 = *(const floatx4*)(h2_lds + tok * 68 + c8);
    floatx4 v1 = *(const floatx4*)(h2_lds + tok * 68 + c8 + 4);
    float s1 = (v0[0]+v0[1])+(v0[2]+v0[3]) + (v1[0]+v1[1])+(v1[2]+v1[3]);
    float s2 = (v0[0]*v0[0]+v0[1]*v0[1])+(v0[2]*v0[2]+v0[3]*v0[3])
             + (v1[0]*v1[0]+v1[1]*v1[1])+(v1[2]*v1[2]+v1[3]*v1[3]);
    #pragma unroll
    for (int d = 1; d < 8; d <<= 1) { s1 += __shfl_xor(s1, d); s2 += __shfl_xor(s2, d); }
    if ((tid & 7) == 0) {
      const float mu = s1 * (1.f / 64.f);
      const float var = s2 * (1.f / 64.f) - mu * mu;
      st_mu[tok] = mu; st_rs[tok] = rsqrtf(var + 1e-5f);
    }
  }
  __syncthreads();

  {
    const float mu = st_mu[tok], rs = st_rs[tok];
    const floatx4 v0 = *(const floatx4*)(h2_lds + tok * 68 + c8);
    const floatx4 v1 = *(const floatx4*)(h2_lds + tok * 68 + c8 + 4);
    const floatx4 ga = *(const floatx4*)(g2 + c8), gb = *(const floatx4*)(g2 + c8 + 4);
    const floatx4 ba = *(const floatx4*)(b2 + c8), bb = *(const floatx4*)(b2 + c8 + 4);
    float hn[8];
    #pragma unroll
    for (int i = 0; i < 4; ++i) {
      hn[i]     = (v0[i] - mu) * rs * ga[i] + ba[i];
      hn[i + 4] = (v1[i] - mu) * rs * gb[i] + bb[i];
    }
    int4v hv;
    hv[0] = pk2(hn[0], hn[1]); hv[1] = pk2(hn[2], hn[3]);
    hv[2] = pk2(hn[4], hn[5]); hv[3] = pk2(hn[6], hn[7]);
    *(int4v*)(hn_lds + tok * 72 + c8) = hv;
  }
  __syncthreads();

  {
    const short8 aA0 = *(const short8*)(hn_lds + (Mt * 16 + mcol) * 72 + quad * 8);
    const short8 aA1 = *(const short8*)(hn_lds + (Mt * 16 + mcol) * 72 + 32 + quad * 8);
    #pragma unroll
    for (int nt = 0; nt < 8; ++nt) {
      const int u0 = ((wid >> 1) * 8 + nt) * 16;
      const short8 b0 = *(const short8*)(w1bf + (u0 + mcol) * 64 + quad * 8);
      const short8 b1 = *(const short8*)(w1bf + (u0 + mcol) * 64 + 32 + quad * 8);
      floatx4 d = (floatx4){0.f,0.f,0.f,0.f};
      d = __builtin_amdgcn_mfma_f32_16x16x32_bf16(aA0, b0, d, 0, 0, 0);
      d = __builtin_amdgcn_mfma_f32_16x16x32_bf16(aA1, b1, d, 0, 0, 0);
      const float bf1v = bf1[u0 + mcol];
      #pragma unroll
      for (int r = 0; r < 4; ++r) {
        const float a = d[r] + bf1v;
        const float gl = 0.5f * a * (1.0f + erff(a * 0.70710678118654752f));
        g_lds[(Mt * 16 + quad * 4 + r) * 264 + u0 + mcol] = f2bf(gl);
      }
    }
  }
  __syncthreads();

  {
    floatx4 acc[2];
    acc[0] = (floatx4){0.f,0.f,0.f,0.f}; acc[1] = (floatx4){0.f,0.f,0.f,0.f};
    #pragma unroll
    for (int ks = 0; ks < 8; ++ks) {
      const short8 aA = *(const short8*)(g_lds + (Mt * 16 + mcol) * 264 + ks * 32 + quad * 8);
      #pragma unroll
      for (int nt = 0; nt < 2; ++nt) {
        const int nc = (nbase + nt) * 16;
        const short8 bB = *(const short8*)(w2bf + (nc + mcol) * 256 + ks * 32 + quad * 8);
        acc[nt] = __builtin_amdgcn_mfma_f32_16x16x32_bf16(aA, bB, acc[nt], 0, 0, 0);
      }
    }
    #pragma unroll
    for (int nt = 0; nt < 2; ++nt) {
      const int cc = (nbase + nt) * 16 + mcol;
      const float g2v = g2[cc], b2v = b2[cc], bf2v = bf2[cc];
      #pragma unroll
      for (int r = 0; r < 4; ++r) {
        const int tokr = Mt * 16 + quad * 4 + r;
        const float hn = (h2_lds[tokr * 68 + cc] - st_mu[tokr]) * st_rs[tokr] * g2v + b2v;
        const float o2 = (hn + acc[nt][r] + bf2v) * maskf[t0 + tokr];
        ot_lds[tokr * 68 + cc] = o2;
      }
    }
  }
  __syncthreads();

  {
    const int c = tid >> 2, tg = (tid & 3) * 8;
    floatx4 v0, v1;
    #pragma unroll
    for (int i = 0; i < 4; ++i) {
      v0[i] = ot_lds[(tg + i) * 68 + c];
      v1[i] = ot_lds[(tg + 4 + i) * 68 + c];
    }
    float* dst = out + ((long)b * 64 + c) * HW + n0 + tg;
    *(floatx4*)dst = v0;
    *(floatx4*)(dst + 4) = v1;
  }
}

// ======================================================================
extern "C" void kernel_launch(void* const* d_in, const int* in_sizes, int n_in,
                              void* d_out, int out_size, void* d_ws, size_t ws_size,
                              hipStream_t stream) {
  (void)in_sizes; (void)n_in; (void)out_size;
  const float* x   = (const float*)d_in[0];
  const int*   msk = (const int*)  d_in[1];
  const float* wq  = (const float*)d_in[2];
  const float* bq  = (const float*)d_in[3];
  const float* wk  = (const float*)d_in[4];
  const float* bk  = (const float*)d_in[5];
  const float* wv  = (const float*)d_in[6];
  const float* bv  = (const float*)d_in[7];
  const float* wo  = (const float*)d_in[8];
  const float* bo  = (const float*)d_in[9];
  const float* g1  = (const float*)d_in[10];
  const float* b1  = (const float*)d_in[11];
  const float* g2  = (const float*)d_in[12];
  const float* b2  = (const float*)d_in[13];
  const float* w1  = (const float*)d_in[14];
  const float* bf1 = (const float*)d_in[15];
  const float* w2  = (const float*)d_in[16];
  const float* bf2 = (const float*)d_in[17];
  float* out = (float*)d_out;

  // SPLITS=16 needs ~48.5 MB of workspace; fall back to 8 if unavailable.
  const size_t NEED16 = 48513056ull;
  const int splits = (ws_size >= NEED16) ? 16 : 8;

  char* ws = (char*)d_ws;
  size_t off = 0;
  unsigned short* h_bf  = (unsigned short*)(ws + off); off += 2359296;
  unsigned short* qg    = (unsigned short*)(ws + off); off += 2359296;
  unsigned short* ksw   = (unsigned short*)(ws + off); off += 2359296;
  unsigned short* vsw   = (unsigned short*)(ws + off); off += 2359296;
  unsigned short* opart = (unsigned short*)(ws + off); off += (size_t)splits * NTOK * 64 * 2;
  float*          lpart = (float*)(ws + off);          off += (size_t)splits * NTOK * 4;
  float*          maskf = (float*)(ws + off);          off += 73728;
  unsigned short* wobf  = (unsigned short*)(ws + off); off += 8192;
  unsigned short* w1bf  = (unsigned short*)(ws + off); off += 32768;
  unsigned short* w2bf  = (unsigned short*)(ws + off); off += 32768;
  float*          nmaskf= (float*)(ws + off);          off += 16;

  hipMemsetAsync(nmaskf, 0, 2 * sizeof(float), stream);   // capture-safe async memset
  k_qkv<<<dim3(576), dim3(256), 0, stream>>>(
      x, wq, bq, wk, bk, wv, bv, g1, b1, msk, wo, w1, w2,
      h_bf, qg, ksw, vsw, maskf, wobf, w1bf, w2bf, nmaskf);
  if (splits == 16) {
    k_attn<16><<<dim3(96 * 16), dim3(256), 0, stream>>>(qg, ksw, vsw, opart, lpart);
    k_post<16><<<dim3(576),     dim3(256), 0, stream>>>(
        opart, lpart, h_bf, maskf, nmaskf, wobf, bo, g2, b2, w1bf, bf1, w2bf, bf2, out);
  } else {
    k_attn<8><<<dim3(96 * 8), dim3(256), 0, stream>>>(qg, ksw, vsw, opart, lpart);
    k_post<8><<<dim3(576),    dim3(256), 0, stream>>>(
        opart, lpart, h_bf, maskf, nmaskf, wobf, bo, g2, b2, w1bf, bf1, w2bf, bf2, out);
  }
}

// Round 8
// 172.510 us; speedup vs baseline: 2.6386x; 1.1799x over previous
//
#include <hip/hip_runtime.h>

// ---- problem constants ----
#define HW     9216
#define NTOK   18432
#define SPLITS 8
#define KIT    (HW / SPLITS / 32)   // 36 tiles of 32 keys

typedef float  floatx4 __attribute__((ext_vector_type(4)));
typedef short  short8  __attribute__((ext_vector_type(8)));
typedef short  short4v __attribute__((ext_vector_type(4)));
typedef int    int4v   __attribute__((ext_vector_type(4)));

#if __has_builtin(__builtin_amdgcn_exp2f)
#define EXP2F(x) __builtin_amdgcn_exp2f(x)
#else
#define EXP2F(x) exp2f(x)
#endif

__device__ __forceinline__ unsigned short f2bf(float f) {   // RNE
  unsigned int u = __float_as_uint(f);
  u += 0x7fffu + ((u >> 16) & 1u);
  return (unsigned short)(u >> 16);
}
__device__ __forceinline__ float bf2f(unsigned short s) {
  return __uint_as_float(((unsigned int)s) << 16);
}
// pack two floats to bf16x2 (round-half-away)
__device__ __forceinline__ int pk2(float a, float b) {
  unsigned ua = __float_as_uint(a) + 0x8000u;
  unsigned ub = __float_as_uint(b) + 0x8000u;
  return (int)((ua >> 16) | (ub & 0xffff0000u));
}

// ======================================================================
// k_qkv: LN1 + Q/K/V projections (wave = 8 tokens). Q scaled by
// C^-0.5*log2e (exp2 fold). Masked tokens' K,V rows zeroed (mask fold;
// p=exp2(0)=1 corrected via per-block counts cntb -- no atomics, no
// memset). K written in natural fragment-tile order; V written with the
// KEY-SLOT PERMUTATION v_pos(16*sub+4q+r) = 8q+4*sub+r, which makes the
// QK^T D-layout register packing directly a valid PV B-fragment in
// k_attn (zero transpose shuffles in the hot loop).
// ======================================================================
__global__ __launch_bounds__(256) void k_qkv(
    const float* __restrict__ x,
    const float* __restrict__ wq, const float* __restrict__ bq,
    const float* __restrict__ wk, const float* __restrict__ bk,
    const float* __restrict__ wv, const float* __restrict__ bv,
    const float* __restrict__ g1, const float* __restrict__ b1,
    const int* __restrict__ mask,
    const float* __restrict__ wo, const float* __restrict__ w1,
    const float* __restrict__ w2,
    unsigned short* __restrict__ h_bf, unsigned short* __restrict__ qg,
    unsigned short* __restrict__ ksw, unsigned short* __restrict__ vsw,
    float* __restrict__ maskf, unsigned short* __restrict__ wobf,
    unsigned short* __restrict__ w1bf, unsigned short* __restrict__ w2bf,
    float* __restrict__ cntb)
{
  __shared__ float xt[64][33];
  __shared__ float hb[32][64];
  __shared__ unsigned short kt[32][72];
  __shared__ unsigned short vt[64][40];

  const int tid = threadIdx.x, wid = tid >> 6, c = tid & 63;
  const int bx = blockIdx.x;
  const int t0 = bx * 32;
  const int b  = t0 / HW, n0 = t0 % HW;

  if (tid < 32) maskf[t0 + tid] = mask[t0 + tid] ? 1.f : 0.f;
  // per-block masked-token count (wave 0 ballot; every slot written)
  if (wid == 0) {
    const bool mm = (c < 32) ? (mask[t0 + c] == 0) : false;
    const unsigned long long bal = __ballot(mm);
    if (c == 0) cntb[bx] = (float)__popcll(bal);
  }
  if (bx < 16)       { const int i = bx * 256 + tid;        wobf[i] = f2bf(wo[i]); }
  else if (bx < 80)  { const int i = (bx - 16) * 256 + tid; w1bf[i] = f2bf(w1[i]); }
  else if (bx < 144) { const int i = (bx - 80) * 256 + tid; w2bf[i] = f2bf(w2[i]); }

  #pragma unroll
  for (int p = 0; p < 2; ++p) {
    const int idx = p * 256 + tid;
    const int cc = idx >> 3, t4 = (idx & 7) * 4;
    const floatx4 v = *(const floatx4*)(x + ((long)b * 64 + cc) * HW + n0 + t4);
    xt[cc][t4 + 0] = v[0]; xt[cc][t4 + 1] = v[1];
    xt[cc][t4 + 2] = v[2]; xt[cc][t4 + 3] = v[3];
  }
  __syncthreads();

  const float g1v = g1[c], b1v = b1[c];
  float aq[8], ak[8], av[8];
  const float bqv = bq[c], bkv = bk[c], bvv = bv[c];

  #pragma unroll
  for (int tt = 0; tt < 8; ++tt) {
    const int tok = wid * 8 + tt;
    const float val = xt[c][tok];
    float s = val, q = val * val;
    #pragma unroll
    for (int d = 1; d < 64; d <<= 1) { s += __shfl_xor(s, d); q += __shfl_xor(q, d); }
    const float mu  = s * (1.f / 64.f);
    const float var = q * (1.f / 64.f) - mu * mu;
    const float hv  = (val - mu) * rsqrtf(var + 1e-5f) * g1v + b1v;
    hb[tok][c] = hv;
    h_bf[(long)(t0 + tok) * 64 + c] = f2bf(hv);
    aq[tt] = bqv; ak[tt] = bkv; av[tt] = bvv;
  }

  const floatx4* wq4 = (const floatx4*)(wq + c * 64);
  const floatx4* wk4 = (const floatx4*)(wk + c * 64);
  const floatx4* wv4 = (const floatx4*)(wv + c * 64);
  #pragma unroll
  for (int i = 0; i < 16; ++i) {
    const floatx4 wqv = wq4[i], wkv = wk4[i], wvv = wv4[i];
    #pragma unroll
    for (int tt = 0; tt < 8; ++tt) {
      const floatx4 hh = *(const floatx4*)&hb[wid * 8 + tt][i * 4];
      aq[tt] = fmaf(wqv[0],hh[0], fmaf(wqv[1],hh[1], fmaf(wqv[2],hh[2], fmaf(wqv[3],hh[3], aq[tt]))));
      ak[tt] = fmaf(wkv[0],hh[0], fmaf(wkv[1],hh[1], fmaf(wkv[2],hh[2], fmaf(wkv[3],hh[3], ak[tt]))));
      av[tt] = fmaf(wvv[0],hh[0], fmaf(wvv[1],hh[1], fmaf(wvv[2],hh[2], fmaf(wvv[3],hh[3], av[tt]))));
    }
  }

  const float QSC = 0.125f * 1.44269504088896f;   // C^-0.5 * log2(e)
  #pragma unroll
  for (int tt = 0; tt < 8; ++tt) {
    const int tok = wid * 8 + tt;
    const float mk = mask[t0 + tok] ? 1.f : 0.f;   // mask fold: zero K,V rows
    qg[(long)(t0 + tok) * 64 + c] = f2bf(aq[tt] * QSC);
    kt[tok][c] = f2bf(ak[tt] * mk);
    vt[c][tok] = f2bf(av[tt] * mk);
  }
  __syncthreads();

  const long tile = (long)b * 288 + (n0 >> 5);
  {
    const int slot = tid >> 6, l = tid & 63;
    const int m = l & 15, qd = l >> 4, sub = slot >> 1, ss = slot & 1;
    const short8 v8 = *(const short8*)(&kt[sub * 16 + m][ss * 32 + qd * 8]);
    *(short8*)(ksw + tile * 2048 + tid * 8) = v8;
  }
  {
    // V with key-slot permutation: slot (qd, j): j<4 -> key 4qd+j (sub0),
    // j>=4 -> key 16+4qd+(j-4) (sub1). Two contiguous b64 reads.
    const int f = tid >> 6, l = tid & 63;
    const int m = l & 15, qd = l >> 4;
    const short4v lo = *(const short4v*)(&vt[f * 16 + m][qd * 4]);
    const short4v hi = *(const short4v*)(&vt[f * 16 + m][16 + qd * 4]);
    short8 v8;
    v8[0] = lo[0]; v8[1] = lo[1]; v8[2] = lo[2]; v8[3] = lo[3];
    v8[4] = hi[0]; v8[5] = hi[1]; v8[6] = hi[2]; v8[7] = hi[3];
    *(short8*)(vsw + tile * 2048 + tid * 8) = v8;
  }
}

// ======================================================================
// k_attn: flash attention, no online max, no mask, NO transpose shuffles
// (V key-permuted at staging), l accumulated via ones-MFMA. K/V double-
// buffered in LDS; waves own disjoint 48-query ranges. Grid 768 = 96
// qblocks x 8 splits = 3 blocks/CU; split = bx&7 pins K/V slice to one
// XCD's L2. launch_bounds(256,4): 128-VGPR cap, compiler ~80, no spills
// (the (256,6) cap in round 6 forced VGPR=40 -> 1.5 GB spill traffic).
// ======================================================================
__global__ __launch_bounds__(256, 4) void k_attn(
    const unsigned short* __restrict__ qg, const unsigned short* __restrict__ ksw,
    const unsigned short* __restrict__ vsw,
    unsigned short* __restrict__ opart, float* __restrict__ lpart)
{
  // [0,4096) K buf0 | [4096,8192) V buf0 | [8192,12288) K buf1 | [12288,16384) V buf1
  // epilogue overlays [0,17408) as per-wave fp32 transpose scratch
  __shared__ __align__(16) char smem[17408];

  const int tid = threadIdx.x, wid = tid >> 6, lane = tid & 63;
  const int mcol = lane & 15, quad = lane >> 4;
  const int bx = blockIdx.x;
  const int split = bx & (SPLITS - 1), qidx = bx / SPLITS;   // qidx 0..95
  const int b = qidx / 48, qt = qidx % 48;
  const long t0q = (long)b * HW + qt * 192 + wid * 48;

  const unsigned short* kswt = ksw + ((long)b * 288 + split * KIT) * 2048;
  const unsigned short* vswt = vsw + ((long)b * 288 + split * KIT) * 2048;

  short8 qf[3][2];
  #pragma unroll
  for (int g = 0; g < 3; ++g)
    #pragma unroll
    for (int s = 0; s < 2; ++s)
      qf[g][s] = *(const short8*)(qg + (t0q + g * 16 + mcol) * 64 + s * 32 + quad * 8);

  short8 ones8;
  #pragma unroll
  for (int i = 0; i < 8; ++i) ones8[i] = (short)0x3F80;   // bf16 1.0

  floatx4 oT[3][4], oL[3];
  #pragma unroll
  for (int g = 0; g < 3; ++g) {
    #pragma unroll
    for (int f = 0; f < 4; ++f) oT[g][f] = (floatx4){0.f,0.f,0.f,0.f};
    oL[g] = (floatx4){0.f,0.f,0.f,0.f};
  }

  short8 kr = *(const short8*)(kswt + tid * 8);
  short8 vr = *(const short8*)(vswt + tid * 8);
  *(short8*)((unsigned short*)smem + tid * 8) = kr;
  *(short8*)((unsigned short*)(smem + 4096) + tid * 8) = vr;
  __syncthreads();

  for (int it = 0; it < KIT; ++it) {
    const int off = (it & 1) * 8192;
    const unsigned short* kfc = (const unsigned short*)(smem + off);
    const unsigned short* vfc = (const unsigned short*)(smem + off + 4096);
    if (it + 1 < KIT) {
      kr = *(const short8*)(kswt + (it + 1) * 2048 + tid * 8);
      vr = *(const short8*)(vswt + (it + 1) * 2048 + tid * 8);
    }

    const short8 kA00 = *(const short8*)(kfc + (0 * 64 + lane) * 8);
    const short8 kA01 = *(const short8*)(kfc + (1 * 64 + lane) * 8);
    const short8 kA10 = *(const short8*)(kfc + (2 * 64 + lane) * 8);
    const short8 kA11 = *(const short8*)(kfc + (3 * 64 + lane) * 8);

    short8 pf[3];
    #pragma unroll
    for (int g = 0; g < 3; ++g) {
      floatx4 s0 = (floatx4){0.f,0.f,0.f,0.f}, s1 = (floatx4){0.f,0.f,0.f,0.f};
      s0 = __builtin_amdgcn_mfma_f32_16x16x32_bf16(kA00, qf[g][0], s0, 0, 0, 0);
      s0 = __builtin_amdgcn_mfma_f32_16x16x32_bf16(kA01, qf[g][1], s0, 0, 0, 0);
      s1 = __builtin_amdgcn_mfma_f32_16x16x32_bf16(kA10, qf[g][0], s1, 0, 0, 0);
      s1 = __builtin_amdgcn_mfma_f32_16x16x32_bf16(kA11, qf[g][1], s1, 0, 0, 0);

      // direct pack: D-layout regs [p0[0..3], p1[0..3]] ARE the B-frag
      // for the key-permuted V (no shuffles)
      int4v pv;
      pv[0] = pk2(EXP2F(s0[0]), EXP2F(s0[1]));
      pv[1] = pk2(EXP2F(s0[2]), EXP2F(s0[3]));
      pv[2] = pk2(EXP2F(s1[0]), EXP2F(s1[1]));
      pv[3] = pk2(EXP2F(s1[2]), EXP2F(s1[3]));
      pf[g] = __builtin_bit_cast(short8, pv);
      // l via ones-MFMA: every D row = sum_k p[k][query]
      oL[g] = __builtin_amdgcn_mfma_f32_16x16x32_bf16(ones8, pf[g], oL[g], 0, 0, 0);
    }

    #pragma unroll
    for (int f = 0; f < 4; ++f) {
      const short8 vA = *(const short8*)(vfc + (f * 64 + lane) * 8);
      #pragma unroll
      for (int g = 0; g < 3; ++g)
        oT[g][f] = __builtin_amdgcn_mfma_f32_16x16x32_bf16(vA, pf[g], oT[g][f], 0, 0, 0);
    }

    if (it + 1 < KIT) {
      unsigned short* kfn = (unsigned short*)(smem + (off ^ 8192));
      unsigned short* vfn = (unsigned short*)(smem + (off ^ 8192) + 4096);
      *(short8*)(kfn + tid * 8) = kr;
      *(short8*)(vfn + tid * 8) = vr;
    }
    __syncthreads();
  }

  // epilogue: per-wave fp32->bf16 transpose through (now free) LDS
  float* scr = (float*)smem + wid * 1088;    // 16 rows x 68
  #pragma unroll
  for (int g = 0; g < 3; ++g) {
    #pragma unroll
    for (int f = 0; f < 4; ++f)
      #pragma unroll
      for (int r = 0; r < 4; ++r)
        scr[(quad * 4 + r) * 68 + f * 16 + mcol] = oT[g][f][r];
    #pragma unroll
    for (int ps = 0; ps < 2; ++ps) {
      const int row = ps * 8 + (lane >> 3), cb = (lane & 7) * 8;
      const floatx4 a = *(const floatx4*)(scr + row * 68 + cb);
      const floatx4 c = *(const floatx4*)(scr + row * 68 + cb + 4);
      int4v pk;
      pk[0] = pk2(a[0], a[1]); pk[1] = pk2(a[2], a[3]);
      pk[2] = pk2(c[0], c[1]); pk[3] = pk2(c[2], c[3]);
      *(int4v*)(opart + ((long)split * NTOK + t0q + g * 16 + row) * 64 + cb) = pk;
    }
  }
  if (lane < 16) {   // quad 0 holds l[query=mcol] in oL[g][0]
    #pragma unroll
    for (int g = 0; g < 3; ++g)
      lpart[(long)split * NTOK + t0q + g * 16 + lane] = oL[g][0];
  }
}

// ======================================================================
// k_post: nmask from cntb (no atomics/memset); merge split partials ->
// att (l corrected); wo-GEMM + residual; LN2; w1-GEMM + exact GELU;
// w2-GEMM + residual; mask; transposed coalesced store.
// ======================================================================
__global__ __launch_bounds__(256) void k_post(
    const unsigned short* __restrict__ opart, const float* __restrict__ lpart,
    const unsigned short* __restrict__ h_bf, const float* __restrict__ maskf,
    const float* __restrict__ cntb,
    const unsigned short* __restrict__ wobf, const float* __restrict__ bo,
    const float* __restrict__ g2, const float* __restrict__ b2,
    const unsigned short* __restrict__ w1bf, const float* __restrict__ bf1,
    const unsigned short* __restrict__ w2bf, const float* __restrict__ bf2,
    float* __restrict__ out)
{
  __shared__ float          h2_lds[32 * 68];
  __shared__ unsigned short att_lds[32 * 72];
  __shared__ unsigned short hn_lds[32 * 72];
  __shared__ unsigned short g_lds[32 * 264];
  __shared__ float          ot_lds[32 * 68];
  __shared__ float          linv[32];
  __shared__ float          st_mu[32], st_rs[32];
  __shared__ float          nred[4];

  const int tid = threadIdx.x, wid = tid >> 6, lane = tid & 63;
  const int mcol = lane & 15, quad = lane >> 4;
  const int t0 = blockIdx.x * 32;
  const int b = t0 / HW, n0 = t0 % HW;

  // nmask = sum of this batch's 288 per-block counts
  {
    float cacc = 0.f;
    for (int i = tid; i < 288; i += 256) cacc += cntb[b * 288 + i];
    #pragma unroll
    for (int d = 1; d < 64; d <<= 1) cacc += __shfl_xor(cacc, d);
    if (lane == 0) nred[wid] = cacc;
  }

  const int tok = tid >> 3, c8 = (tid & 7) * 8;
  float o[8];
  #pragma unroll
  for (int i = 0; i < 8; ++i) o[i] = 0.f;
  #pragma unroll
  for (int s = 0; s < SPLITS; ++s) {
    const short8 op = *(const short8*)(opart + ((long)s * NTOK + t0 + tok) * 64 + c8);
    #pragma unroll
    for (int i = 0; i < 8; ++i) o[i] += bf2f((unsigned short)op[i]);
  }
  const short8 hb8 = *(const short8*)(h_bf + (long)(t0 + tok) * 64 + c8);
  const floatx4 bo0 = *(const floatx4*)(bo + c8);
  const floatx4 bo1 = *(const floatx4*)(bo + c8 + 4);
  __syncthreads();

  if (tid < 32) {
    float l = -((nred[0] + nred[1]) + (nred[2] + nred[3]));   // mask-fold correction
    #pragma unroll
    for (int s = 0; s < SPLITS; ++s) l += lpart[(long)s * NTOK + t0 + tid];
    linv[tid] = 1.0f / l;
  }
  __syncthreads();
  {
    const float sc = linv[tok];
    int4v av;
    av[0] = pk2(o[0]*sc, o[1]*sc); av[1] = pk2(o[2]*sc, o[3]*sc);
    av[2] = pk2(o[4]*sc, o[5]*sc); av[3] = pk2(o[6]*sc, o[7]*sc);
    *(int4v*)(att_lds + tok * 72 + c8) = av;
    floatx4 h20, h21;
    #pragma unroll
    for (int i = 0; i < 4; ++i) {
      h20[i] = bf2f((unsigned short)hb8[i])     + bo0[i];
      h21[i] = bf2f((unsigned short)hb8[i + 4]) + bo1[i];
    }
    *(floatx4*)(h2_lds + tok * 68 + c8)     = h20;
    *(floatx4*)(h2_lds + tok * 68 + c8 + 4) = h21;
  }
  __syncthreads();

  const int Mt = wid & 1, nbase = (wid >> 1) * 2;
  {
    const short8 aA0 = *(const short8*)(att_lds + (Mt * 16 + mcol) * 72 + quad * 8);
    const short8 aA1 = *(const short8*)(att_lds + (Mt * 16 + mcol) * 72 + 32 + quad * 8);
    #pragma unroll
    for (int nt = 0; nt < 2; ++nt) {
      const int nc = (nbase + nt) * 16;
      const short8 b0 = *(const short8*)(wobf + (nc + mcol) * 64 + quad * 8);
      const short8 b1 = *(const short8*)(wobf + (nc + mcol) * 64 + 32 + quad * 8);
      floatx4 d = (floatx4){0.f,0.f,0.f,0.f};
      d = __builtin_amdgcn_mfma_f32_16x16x32_bf16(aA0, b0, d, 0, 0, 0);
      d = __builtin_amdgcn_mfma_f32_16x16x32_bf16(aA1, b1, d, 0, 0, 0);
      #pragma unroll
      for (int r = 0; r < 4; ++r)
        h2_lds[(Mt * 16 + quad * 4 + r) * 68 + nc + mcol] += d[r];
    }
  }
  __syncthreads();

  {
    floatx4 v0 = *(const floatx4*)(h2_lds + tok * 68 + c8);
    floatx4 v1 = *(const floatx4*)(h2_lds + tok * 68 + c8 + 4);
    float s1 = (v0[0]+v0[1])+(v0[2]+v0[3]) + (v1[0]+v1[1])+(v1[2]+v1[3]);
    float s2 = (v0[0]*v0[0]+v0[1]*v0[1])+(v0[2]*v0[2]+v0[3]*v0[3])
             + (v1[0]*v1[0]+v1[1]*v1[1])+(v1[2]*v1[2]+v1[3]*v1[3]);
    #pragma unroll
    for (int d = 1; d < 8; d <<= 1) { s1 += __shfl_xor(s1, d); s2 += __shfl_xor(s2, d); }
    if ((tid & 7) == 0) {
      const float mu = s1 * (1.f / 64.f);
      const float var = s2 * (1.f / 64.f) - mu * mu;
      st_mu[tok] = mu; st_rs[tok] = rsqrtf(var + 1e-5f);
    }
  }
  __syncthreads();

  {
    const float mu = st_mu[tok], rs = st_rs[tok];
    const floatx4 v0 = *(const floatx4*)(h2_lds + tok * 68 + c8);
    const floatx4 v1 = *(const floatx4*)(h2_lds + tok * 68 + c8 + 4);
    const floatx4 ga = *(const floatx4*)(g2 + c8), gb = *(const floatx4*)(g2 + c8 + 4);
    const floatx4 ba = *(const floatx4*)(b2 + c8), bb = *(const floatx4*)(b2 + c8 + 4);
    float hn[8];
    #pragma unroll
    for (int i = 0; i < 4; ++i) {
      hn[i]     = (v0[i] - mu) * rs * ga[i] + ba[i];
      hn[i + 4] = (v1[i] - mu) * rs * gb[i] + bb[i];
    }
    int4v hv;
    hv[0] = pk2(hn[0], hn[1]); hv[1] = pk2(hn[2], hn[3]);
    hv[2] = pk2(hn[4], hn[5]); hv[3] = pk2(hn[6], hn[7]);
    *(int4v*)(hn_lds + tok * 72 + c8) = hv;
  }
  __syncthreads();

  {
    const short8 aA0 = *(const short8*)(hn_lds + (Mt * 16 + mcol) * 72 + quad * 8);
    const short8 aA1 = *(const short8*)(hn_lds + (Mt * 16 + mcol) * 72 + 32 + quad * 8);
    #pragma unroll
    for (int nt = 0; nt < 8; ++nt) {
      const int u0 = ((wid >> 1) * 8 + nt) * 16;
      const short8 b0 = *(const short8*)(w1bf + (u0 + mcol) * 64 + quad * 8);
      const short8 b1 = *(const short8*)(w1bf + (u0 + mcol) * 64 + 32 + quad * 8);
      floatx4 d = (floatx4){0.f,0.f,0.f,0.f};
      d = __builtin_amdgcn_mfma_f32_16x16x32_bf16(aA0, b0, d, 0, 0, 0);
      d = __builtin_amdgcn_mfma_f32_16x16x32_bf16(aA1, b1, d, 0, 0, 0);
      const float bf1v = bf1[u0 + mcol];
      #pragma unroll
      for (int r = 0; r < 4; ++r) {
        const float a = d[r] + bf1v;
        const float gl = 0.5f * a * (1.0f + erff(a * 0.70710678118654752f));
        g_lds[(Mt * 16 + quad * 4 + r) * 264 + u0 + mcol] = f2bf(gl);
      }
    }
  }
  __syncthreads();

  {
    floatx4 acc[2];
    acc[0] = (floatx4){0.f,0.f,0.f,0.f}; acc[1] = (floatx4){0.f,0.f,0.f,0.f};
    #pragma unroll
    for (int ks = 0; ks < 8; ++ks) {
      const short8 aA = *(const short8*)(g_lds + (Mt * 16 + mcol) * 264 + ks * 32 + quad * 8);
      #pragma unroll
      for (int nt = 0; nt < 2; ++nt) {
        const int nc = (nbase + nt) * 16;
        const short8 bB = *(const short8*)(w2bf + (nc + mcol) * 256 + ks * 32 + quad * 8);
        acc[nt] = __builtin_amdgcn_mfma_f32_16x16x32_bf16(aA, bB, acc[nt], 0, 0, 0);
      }
    }
    #pragma unroll
    for (int nt = 0; nt < 2; ++nt) {
      const int cc = (nbase + nt) * 16 + mcol;
      const float g2v = g2[cc], b2v = b2[cc], bf2v = bf2[cc];
      #pragma unroll
      for (int r = 0; r < 4; ++r) {
        const int tokr = Mt * 16 + quad * 4 + r;
        const float hn = (h2_lds[tokr * 68 + cc] - st_mu[tokr]) * st_rs[tokr] * g2v + b2v;
        const float o2 = (hn + acc[nt][r] + bf2v) * maskf[t0 + tokr];
        ot_lds[tokr * 68 + cc] = o2;
      }
    }
  }
  __syncthreads();

  {
    const int c = tid >> 2, tg = (tid & 3) * 8;
    floatx4 v0, v1;
    #pragma unroll
    for (int i = 0; i < 4; ++i) {
      v0[i] = ot_lds[(tg + i) * 68 + c];
      v1[i] = ot_lds[(tg + 4 + i) * 68 + c];
    }
    float* dst = out + ((long)b * 64 + c) * HW + n0 + tg;
    *(floatx4*)dst = v0;
    *(floatx4*)(dst + 4) = v1;
  }
}

// ======================================================================
extern "C" void kernel_launch(void* const* d_in, const int* in_sizes, int n_in,
                              void* d_out, int out_size, void* d_ws, size_t ws_size,
                              hipStream_t stream) {
  (void)in_sizes; (void)n_in; (void)out_size; (void)ws_size;
  const float* x   = (const float*)d_in[0];
  const int*   msk = (const int*)  d_in[1];
  const float* wq  = (const float*)d_in[2];
  const float* bq  = (const float*)d_in[3];
  const float* wk  = (const float*)d_in[4];
  const float* bk  = (const float*)d_in[5];
  const float* wv  = (const float*)d_in[6];
  const float* bv  = (const float*)d_in[7];
  const float* wo  = (const float*)d_in[8];
  const float* bo  = (const float*)d_in[9];
  const float* g1  = (const float*)d_in[10];
  const float* b1  = (const float*)d_in[11];
  const float* g2  = (const float*)d_in[12];
  const float* b2  = (const float*)d_in[13];
  const float* w1  = (const float*)d_in[14];
  const float* bf1 = (const float*)d_in[15];
  const float* w2  = (const float*)d_in[16];
  const float* bf2 = (const float*)d_in[17];
  float* out = (float*)d_out;

  // workspace layout (bytes), 16B-aligned; total ~28.8 MB
  char* ws = (char*)d_ws;
  size_t off = 0;
  unsigned short* h_bf  = (unsigned short*)(ws + off); off += 2359296;
  unsigned short* qg    = (unsigned short*)(ws + off); off += 2359296;
  unsigned short* ksw   = (unsigned short*)(ws + off); off += 2359296;
  unsigned short* vsw   = (unsigned short*)(ws + off); off += 2359296;
  unsigned short* opart = (unsigned short*)(ws + off); off += (size_t)SPLITS * NTOK * 64 * 2;
  float*          lpart = (float*)(ws + off);          off += (size_t)SPLITS * NTOK * 4;
  float*          maskf = (float*)(ws + off);          off += 73728;
  unsigned short* wobf  = (unsigned short*)(ws + off); off += 8192;
  unsigned short* w1bf  = (unsigned short*)(ws + off); off += 32768;
  unsigned short* w2bf  = (unsigned short*)(ws + off); off += 32768;
  float*          cntb  = (float*)(ws + off);          off += 2304;

  k_qkv<<<dim3(576), dim3(256), 0, stream>>>(
      x, wq, bq, wk, bk, wv, bv, g1, b1, msk, wo, w1, w2,
      h_bf, qg, ksw, vsw, maskf, wobf, w1bf, w2bf, cntb);
  k_attn<<<dim3(96 * SPLITS), dim3(256), 0, stream>>>(qg, ksw, vsw, opart, lpart);
  k_post<<<dim3(576), dim3(256), 0, stream>>>(
      opart, lpart, h_bf, maskf, cntb, wobf, bo, g2, b2, w1bf, bf1, w2bf, bf2, out);
}